// Round 1
// baseline (1796.323 us; speedup 1.0000x reference)
//
#include <hip/hip_runtime.h>
#include <math.h>

#define Bb 32
#define Nn 2048
#define Dd 512
#define NS 8
#define ITERS 3
#define EPSf 1e-8f
#define SCALEf 0.04419417382415922f   // 512^-0.5
#define LN_EPSf 1e-5f

// ---------------- wave reduce ----------------
__device__ __forceinline__ float waveReduceSum(float v) {
    #pragma unroll
    for (int m = 32; m >= 1; m >>= 1) v += __shfl_xor(v, m);
    return v;
}

__device__ __forceinline__ float gelu_exact(float x) {
    return 0.5f * x * (1.0f + erff(x * 0.7071067811865476f));
}

// ---------------- LN stats for inputs (wave per row of 512) ----------------
__global__ __launch_bounds__(256) void ln_stats_kernel(
    const float* __restrict__ x, float* __restrict__ mean, float* __restrict__ rstd, int rows) {
    int wid = blockIdx.x * 4 + (threadIdx.x >> 6);
    int lane = threadIdx.x & 63;
    if (wid >= rows) return;
    const float* row = x + (size_t)wid * Dd;
    float s = 0.f, sq = 0.f;
    #pragma unroll
    for (int t = 0; t < 8; ++t) {
        float v = row[t * 64 + lane];
        s += v; sq += v * v;
    }
    s = waveReduceSum(s);
    sq = waveReduceSum(sq);
    if (lane == 0) {
        float m = s * (1.0f / Dd);
        float var = sq * (1.0f / Dd) - m * m;
        mean[wid] = m;
        rstd[wid] = rsqrtf(var + LN_EPSf);
    }
}

// ---------------- LN apply (wave per row of 512), y = (x-m)*rs*g + b ----------------
__global__ __launch_bounds__(256) void ln_apply_kernel(
    const float* __restrict__ x, float* __restrict__ y,
    const float* __restrict__ g, const float* __restrict__ b, int rows) {
    int wid = blockIdx.x * 4 + (threadIdx.x >> 6);
    int lane = threadIdx.x & 63;
    if (wid >= rows) return;
    const float* row = x + (size_t)wid * Dd;
    float v[8];
    float s = 0.f, sq = 0.f;
    #pragma unroll
    for (int t = 0; t < 8; ++t) {
        v[t] = row[t * 64 + lane];
        s += v[t]; sq += v[t] * v[t];
    }
    s = waveReduceSum(s);
    sq = waveReduceSum(sq);
    float m = s * (1.0f / Dd);
    float var = sq * (1.0f / Dd) - m * m;
    float rs = rsqrtf(var + LN_EPSf);
    float* out = y + (size_t)wid * Dd;
    #pragma unroll
    for (int t = 0; t < 8; ++t) {
        int d = t * 64 + lane;
        out[d] = (v[t] - m) * rs * g[d] + b[d];
    }
}

// ---------------- slot init: mu + exp(logsigma)*noise ----------------
__global__ __launch_bounds__(256) void slots_init_kernel(
    const float* __restrict__ noise, const float* __restrict__ mu,
    const float* __restrict__ ls, float* __restrict__ slots) {
    int idx = blockIdx.x * 256 + threadIdx.x;
    if (idx >= Bb * NS * Dd) return;
    int d = idx & (Dd - 1);
    slots[idx] = mu[d] + expf(ls[d]) * noise[idx];
}

// ---------------- k/v projection GEMM with LN(A) fused ----------------
// C = LN(X) @ W^T + bias ; X [65536,512]; W = k_w or v_w per n0 block.
// Tile 64x64x32, 256 threads, 4x4 per thread.
__global__ __launch_bounds__(256) void kv_gemm_kernel(
    const float* __restrict__ X, const float* __restrict__ mean, const float* __restrict__ rstd,
    const float* __restrict__ ln_g, const float* __restrict__ ln_b,
    const float* __restrict__ k_w, const float* __restrict__ k_b,
    const float* __restrict__ v_w, const float* __restrict__ v_b,
    float* __restrict__ Kb, float* __restrict__ Vb) {
    __shared__ float As[32][68];
    __shared__ float Bs[32][68];
    const int tid = threadIdx.x;
    const int tx = tid & 15, ty = tid >> 4;
    const int m0 = blockIdx.y * 64;
    const int n0 = blockIdx.x * 64;          // 0..1023 ; <512 -> k, else v
    const bool isK = (n0 < 512);
    const float* __restrict__ Wp = isK ? k_w : v_w;
    const float* __restrict__ bp = isK ? k_b : v_b;
    float* __restrict__ Cout = isK ? Kb : Vb;
    const int ncol0 = isK ? n0 : (n0 - 512);

    float acc[4][4] = {};
    for (int k0 = 0; k0 < Dd; k0 += 32) {
        __syncthreads();
        #pragma unroll
        for (int p = 0; p < 2; ++p) {
            int idx4 = tid + p * 256;
            int row = idx4 >> 3, c4 = idx4 & 7;
            // A: LN on the fly
            float4 xv = *(const float4*)(X + (size_t)(m0 + row) * Dd + k0 + c4 * 4);
            float mr = mean[m0 + row], rr = rstd[m0 + row];
            float4 gv = *(const float4*)(ln_g + k0 + c4 * 4);
            float4 bv = *(const float4*)(ln_b + k0 + c4 * 4);
            As[c4 * 4 + 0][row] = (xv.x - mr) * rr * gv.x + bv.x;
            As[c4 * 4 + 1][row] = (xv.y - mr) * rr * gv.y + bv.y;
            As[c4 * 4 + 2][row] = (xv.z - mr) * rr * gv.z + bv.z;
            As[c4 * 4 + 3][row] = (xv.w - mr) * rr * gv.w + bv.w;
            float4 wv = *(const float4*)(Wp + (size_t)(ncol0 + row) * Dd + k0 + c4 * 4);
            Bs[c4 * 4 + 0][row] = wv.x;
            Bs[c4 * 4 + 1][row] = wv.y;
            Bs[c4 * 4 + 2][row] = wv.z;
            Bs[c4 * 4 + 3][row] = wv.w;
        }
        __syncthreads();
        #pragma unroll
        for (int kk = 0; kk < 32; ++kk) {
            float a[4], b[4];
            #pragma unroll
            for (int i = 0; i < 4; ++i) a[i] = As[kk][ty * 4 + i];
            #pragma unroll
            for (int j = 0; j < 4; ++j) b[j] = Bs[kk][tx * 4 + j];
            #pragma unroll
            for (int i = 0; i < 4; ++i)
                #pragma unroll
                for (int j = 0; j < 4; ++j) acc[i][j] += a[i] * b[j];
        }
    }
    #pragma unroll
    for (int i = 0; i < 4; ++i) {
        int m = m0 + ty * 4 + i;
        int c = ncol0 + tx * 4;
        float4 o;
        o.x = acc[i][0] + bp[c + 0];
        o.y = acc[i][1] + bp[c + 1];
        o.z = acc[i][2] + bp[c + 2];
        o.w = acc[i][3] + bp[c + 3];
        *(float4*)(Cout + (size_t)m * Dd + c) = o;
    }
}

// ---------------- generic GEMM: C = act(A[M,K] @ Bw[N,K]^T + bias) ----------------
template <int ACT>
__global__ __launch_bounds__(256) void gemm_bt_kernel(
    const float* __restrict__ A, const float* __restrict__ Bw,
    const float* __restrict__ bias, float* __restrict__ C,
    int M, int N, int K) {
    __shared__ float As[32][68];
    __shared__ float Bs[32][68];
    const int tid = threadIdx.x;
    const int tx = tid & 15, ty = tid >> 4;
    const int m0 = blockIdx.y * 64;
    const int n0 = blockIdx.x * 64;
    float acc[4][4] = {};
    for (int k0 = 0; k0 < K; k0 += 32) {
        __syncthreads();
        #pragma unroll
        for (int p = 0; p < 2; ++p) {
            int idx4 = tid + p * 256;
            int row = idx4 >> 3, c4 = idx4 & 7;
            float4 av = *(const float4*)(A + (size_t)(m0 + row) * K + k0 + c4 * 4);
            As[c4 * 4 + 0][row] = av.x;
            As[c4 * 4 + 1][row] = av.y;
            As[c4 * 4 + 2][row] = av.z;
            As[c4 * 4 + 3][row] = av.w;
            float4 bv = *(const float4*)(Bw + (size_t)(n0 + row) * K + k0 + c4 * 4);
            Bs[c4 * 4 + 0][row] = bv.x;
            Bs[c4 * 4 + 1][row] = bv.y;
            Bs[c4 * 4 + 2][row] = bv.z;
            Bs[c4 * 4 + 3][row] = bv.w;
        }
        __syncthreads();
        #pragma unroll
        for (int kk = 0; kk < 32; ++kk) {
            float a[4], b[4];
            #pragma unroll
            for (int i = 0; i < 4; ++i) a[i] = As[kk][ty * 4 + i];
            #pragma unroll
            for (int j = 0; j < 4; ++j) b[j] = Bs[kk][tx * 4 + j];
            #pragma unroll
            for (int i = 0; i < 4; ++i)
                #pragma unroll
                for (int j = 0; j < 4; ++j) acc[i][j] += a[i] * b[j];
        }
    }
    #pragma unroll
    for (int i = 0; i < 4; ++i) {
        int m = m0 + ty * 4 + i;
        int c = n0 + tx * 4;
        float4 o;
        o.x = acc[i][0] + bias[c + 0];
        o.y = acc[i][1] + bias[c + 1];
        o.z = acc[i][2] + bias[c + 2];
        o.w = acc[i][3] + bias[c + 3];
        if (ACT == 1) {
            o.x = gelu_exact(o.x); o.y = gelu_exact(o.y);
            o.z = gelu_exact(o.z); o.w = gelu_exact(o.w);
        }
        *(float4*)(C + (size_t)m * N + c) = o;
    }
}

// ---------------- dots: dotsT[b, j, i] = SCALE * q[b,i,:] . k[b,j,:] ----------------
// grid (32 chunks of 64 tokens, B); block 256 = 4 waves; wave handles 16 tokens.
__global__ __launch_bounds__(256) void dots_kernel(
    const float* __restrict__ q, const float* __restrict__ k, float* __restrict__ dotsT) {
    const int b = blockIdx.y;
    const int chunk = blockIdx.x;
    __shared__ float qs[NS * Dd];
    const int tid = threadIdx.x;
    const float4* q4 = (const float4*)(q + (size_t)b * NS * Dd);
    float4* qs4 = (float4*)qs;
    #pragma unroll
    for (int p = 0; p < 4; ++p) qs4[tid + p * 256] = q4[tid + p * 256];
    __syncthreads();
    const int wave = tid >> 6, lane = tid & 63;
    for (int t = 0; t < 16; ++t) {
        int j = chunk * 64 + wave * 16 + t;
        const float* krow = k + ((size_t)b * Nn + j) * Dd;
        float acc[NS] = {};
        #pragma unroll
        for (int seg = 0; seg < 8; ++seg) {
            float kv = krow[seg * 64 + lane];
            #pragma unroll
            for (int i = 0; i < NS; ++i) acc[i] += qs[i * Dd + seg * 64 + lane] * kv;
        }
        float res = 0.f;
        #pragma unroll
        for (int i = 0; i < NS; ++i) {
            float v = acc[i];
            #pragma unroll
            for (int m = 32; m >= 1; m >>= 1) v += __shfl_xor(v, m);
            if (lane == i) res = v;
        }
        if (lane < NS) dotsT[((size_t)b * Nn + j) * NS + lane] = res * SCALEf;
    }
}

// ---------------- softmax over slots (contiguous 8) + EPS; accumulate token sums ----------------
__global__ __launch_bounds__(256) void softmax_kernel(
    float* __restrict__ att, float* __restrict__ sums) {
    int idx = blockIdx.x * 256 + threadIdx.x;  // one per (b, j); 65536 total
    int b = idx >> 11;
    float4 x0 = ((float4*)att)[idx * 2];
    float4 x1 = ((float4*)att)[idx * 2 + 1];
    float v[8] = {x0.x, x0.y, x0.z, x0.w, x1.x, x1.y, x1.z, x1.w};
    float m = v[0];
    #pragma unroll
    for (int i = 1; i < 8; ++i) m = fmaxf(m, v[i]);
    float s = 0.f;
    #pragma unroll
    for (int i = 0; i < 8; ++i) { v[i] = expf(v[i] - m); s += v[i]; }
    float inv = 1.0f / s;
    #pragma unroll
    for (int i = 0; i < 8; ++i) v[i] = v[i] * inv + EPSf;
    float4 o0 = {v[0], v[1], v[2], v[3]};
    float4 o1 = {v[4], v[5], v[6], v[7]};
    ((float4*)att)[idx * 2] = o0;
    ((float4*)att)[idx * 2 + 1] = o1;
    int lane = threadIdx.x & 63;
    #pragma unroll
    for (int i = 0; i < 8; ++i) {
        float t = waveReduceSum(v[i]);
        if (lane == 0) atomicAdd(&sums[b * NS + i], t);
    }
}

// ---------------- updates accumulation: raw[b,i,d] += sum_j att[b,j,i] * v[b,j,d] ----------------
// grid (16 token-chunks of 128, B); block 256; thread owns 2 d-cols.
__global__ __launch_bounds__(256) void updates_kernel(
    const float* __restrict__ att, const float* __restrict__ v, float* __restrict__ raw) {
    const int b = blockIdx.y;
    const int jc = blockIdx.x;
    const int tid = threadIdx.x;
    __shared__ float asm_[64 * NS];
    float2 acc[NS];
    #pragma unroll
    for (int i = 0; i < NS; ++i) { acc[i].x = 0.f; acc[i].y = 0.f; }
    for (int g = 0; g < 2; ++g) {
        int j0 = jc * 128 + g * 64;
        __syncthreads();
        ((float2*)asm_)[tid] = ((const float2*)(att + ((size_t)b * Nn + j0) * NS))[tid];
        __syncthreads();
        for (int jl = 0; jl < 64; ++jl) {
            float2 vv = *(const float2*)(v + ((size_t)b * Nn + j0 + jl) * Dd + tid * 2);
            #pragma unroll
            for (int i = 0; i < NS; ++i) {
                float a = asm_[jl * NS + i];
                acc[i].x += a * vv.x;
                acc[i].y += a * vv.y;
            }
        }
    }
    #pragma unroll
    for (int i = 0; i < NS; ++i) {
        float* p = raw + ((size_t)(b * NS + i)) * Dd + tid * 2;
        atomicAdd(p, acc[i].x);
        atomicAdd(p + 1, acc[i].y);
    }
}

// ---------------- finalize: u = raw / sums ; also write output 0 ----------------
__global__ __launch_bounds__(256) void finalize_kernel(
    const float* __restrict__ raw, const float* __restrict__ sums,
    float* __restrict__ u, float* __restrict__ out0) {
    int idx = blockIdx.x * 256 + threadIdx.x;
    if (idx >= Bb * NS * Dd) return;
    int row = idx >> 9;
    float val = raw[idx] / sums[row];
    u[idx] = val;
    out0[idx] = val;
}

// ---------------- GRU elementwise; slots updated in place ----------------
__global__ __launch_bounds__(256) void gru_elem_kernel(
    const float* __restrict__ gi, const float* __restrict__ gh,
    const float* __restrict__ u, float* __restrict__ slots) {
    int idx = blockIdx.x * 256 + threadIdx.x;
    if (idx >= Bb * NS * Dd) return;
    int row = idx >> 9, d = idx & (Dd - 1);
    const float* gir = gi + (size_t)row * 1536;
    const float* ghr = gh + (size_t)row * 1536;
    float ir = gir[d], iz = gir[512 + d], in_ = gir[1024 + d];
    float hr = ghr[d], hz = ghr[512 + d], hn = ghr[1024 + d];
    float r = 1.0f / (1.0f + expf(-(ir + hr)));
    float z = 1.0f / (1.0f + expf(-(iz + hz)));
    float n = tanhf(in_ + r * hn);
    float h = slots[idx];
    float hnew = (1.0f - z) * n + z * h;
    slots[idx] = u[idx] + hnew;
}

// ---------------- launch ----------------
extern "C" void kernel_launch(void* const* d_in, const int* in_sizes, int n_in,
                              void* d_out, int out_size, void* d_ws, size_t ws_size,
                              hipStream_t stream) {
    const float* inputs   = (const float*)d_in[0];
    const float* noise    = (const float*)d_in[1];
    const float* mu       = (const float*)d_in[2];
    const float* lsig     = (const float*)d_in[3];
    const float* k_w      = (const float*)d_in[4];
    const float* k_b      = (const float*)d_in[5];
    const float* v_w      = (const float*)d_in[6];
    const float* v_b      = (const float*)d_in[7];
    const float* w_ih     = (const float*)d_in[8];
    const float* w_hh     = (const float*)d_in[9];
    const float* b_ih     = (const float*)d_in[10];
    const float* b_hh     = (const float*)d_in[11];
    const float* ln_in_g  = (const float*)d_in[12];
    const float* ln_in_b  = (const float*)d_in[13];
    const float* ln_s_g   = (const float*)d_in[14];
    const float* ln_s_b   = (const float*)d_in[15];
    const float* ln_p_g   = (const float*)d_in[16];
    const float* ln_p_b   = (const float*)d_in[17];
    const float* mlp1_w   = (const float*)d_in[18];
    const float* mlp1_b   = (const float*)d_in[19];
    const float* mlp2_w   = (const float*)d_in[20];
    const float* mlp2_b   = (const float*)d_in[21];
    const float* mlp3_w   = (const float*)d_in[22];
    const float* mlp3_b   = (const float*)d_in[23];
    const float* mlp4_w   = (const float*)d_in[24];
    const float* mlp4_b   = (const float*)d_in[25];
    float* out0 = (float*)d_out;                 // updates [32,8,512]
    float* out1 = (float*)d_out + Bb * NS * Dd;  // s [32,8,256]

    char* wp = (char*)d_ws;
    auto alloc = [&](size_t bytes) -> float* {
        float* p = (float*)wp;
        wp += (bytes + 255) & ~(size_t)255;
        return p;
    };
    const size_t MR = (size_t)Bb * Nn;           // 65536 rows
    float* kbuf  = alloc(MR * Dd * 4);           // 134 MB
    float* vbuf  = alloc(MR * Dd * 4);           // 134 MB
    float* meanb = alloc(MR * 4);
    float* rstdb = alloc(MR * 4);
    float* slots = alloc((size_t)Bb * NS * Dd * 4);
    float* qbuf  = alloc((size_t)Bb * NS * Dd * 4);
    float* att   = alloc((size_t)Bb * Nn * NS * 4);
    float* sums  = alloc((size_t)Bb * NS * 4);
    float* raw   = alloc((size_t)Bb * NS * Dd * 4);
    float* ubuf  = alloc((size_t)Bb * NS * Dd * 4);
    float* gi    = alloc((size_t)Bb * NS * 1536 * 4);
    float* gh    = alloc((size_t)Bb * NS * 1536 * 4);
    float* sln   = alloc((size_t)Bb * NS * Dd * 4);
    float* h1    = alloc((size_t)Bb * NS * 1024 * 4);
    float* h2    = alloc((size_t)Bb * NS * 1024 * 4);
    float* h3    = alloc((size_t)Bb * NS * Dd * 4);

    // Phase 1: LN stats + fused k/v projection + slot init
    ln_stats_kernel<<<MR / 4, 256, 0, stream>>>(inputs, meanb, rstdb, (int)MR);
    kv_gemm_kernel<<<dim3(16, MR / 64), 256, 0, stream>>>(
        inputs, meanb, rstdb, ln_in_g, ln_in_b, k_w, k_b, v_w, v_b, kbuf, vbuf);
    slots_init_kernel<<<(Bb * NS * Dd) / 256, 256, 0, stream>>>(noise, mu, lsig, slots);

    for (int it = 0; it < ITERS; ++it) {
        ln_apply_kernel<<<(Bb * NS) / 4, 256, 0, stream>>>(slots, qbuf, ln_s_g, ln_s_b, Bb * NS);
        dots_kernel<<<dim3(32, Bb), 256, 0, stream>>>(qbuf, kbuf, att);
        hipMemsetAsync(sums, 0, Bb * NS * 4, stream);
        softmax_kernel<<<(Bb * Nn) / 256, 256, 0, stream>>>(att, sums);
        hipMemsetAsync(raw, 0, (size_t)Bb * NS * Dd * 4, stream);
        updates_kernel<<<dim3(16, Bb), 256, 0, stream>>>(att, vbuf, raw);
        finalize_kernel<<<(Bb * NS * Dd) / 256, 256, 0, stream>>>(raw, sums, ubuf, out0);
        gemm_bt_kernel<0><<<dim3(1536 / 64, 256 / 64), 256, 0, stream>>>(
            ubuf, w_ih, b_ih, gi, 256, 1536, 512);
        gemm_bt_kernel<0><<<dim3(1536 / 64, 256 / 64), 256, 0, stream>>>(
            slots, w_hh, b_hh, gh, 256, 1536, 512);
        gru_elem_kernel<<<(Bb * NS * Dd) / 256, 256, 0, stream>>>(gi, gh, ubuf, slots);
    }

    // Output MLP
    ln_apply_kernel<<<(Bb * NS) / 4, 256, 0, stream>>>(slots, sln, ln_p_g, ln_p_b, Bb * NS);
    gemm_bt_kernel<1><<<dim3(1024 / 64, 4), 256, 0, stream>>>(sln, mlp1_w, mlp1_b, h1, 256, 1024, 512);
    gemm_bt_kernel<1><<<dim3(1024 / 64, 4), 256, 0, stream>>>(h1, mlp2_w, mlp2_b, h2, 256, 1024, 1024);
    gemm_bt_kernel<1><<<dim3(512 / 64, 4), 256, 0, stream>>>(h2, mlp3_w, mlp3_b, h3, 256, 512, 1024);
    gemm_bt_kernel<0><<<dim3(256 / 64, 4), 256, 0, stream>>>(h3, mlp4_w, mlp4_b, out1, 256, 256, 512);
}

// Round 2
// 1090.509 us; speedup vs baseline: 1.6472x; 1.6472x over previous
//
#include <hip/hip_runtime.h>
#include <math.h>

#define Bb 32
#define Nn 2048
#define Dd 512
#define NS 8
#define ITERS 3
#define EPSf 1e-8f
#define SCALEf 0.04419417382415922f   // 512^-0.5
#define LN_EPSf 1e-5f

typedef _Float16 half8 __attribute__((ext_vector_type(8)));
typedef float f32x4 __attribute__((ext_vector_type(4)));

__device__ __forceinline__ float waveReduceSum(float v) {
    #pragma unroll
    for (int m = 32; m >= 1; m >>= 1) v += __shfl_xor(v, m);
    return v;
}

__device__ __forceinline__ float gelu_exact(float x) {
    return 0.5f * x * (1.0f + erff(x * 0.7071067811865476f));
}

// async global->LDS, 16B per lane; LDS dst = wave-uniform base + lane*16
__device__ __forceinline__ void async_copy16(const _Float16* g, _Float16* l) {
    __builtin_amdgcn_global_load_lds(
        (const __attribute__((address_space(1))) unsigned int*)g,
        (__attribute__((address_space(3))) unsigned int*)l, 16, 0, 0);
}

// ---------------- packing kernels ----------------
// LN(inputs) -> split fp16 hi|lo, row layout [hi(512) | lo(512)]
__global__ __launch_bounds__(256) void pack_ln_split_kernel(
    const float* __restrict__ x, const float* __restrict__ g, const float* __restrict__ b,
    _Float16* __restrict__ Ap) {
    int wid = blockIdx.x * 4 + (threadIdx.x >> 6);
    int lane = threadIdx.x & 63;
    const float* row = x + (size_t)wid * Dd;
    float v[8];
    float s = 0.f, sq = 0.f;
    #pragma unroll
    for (int t = 0; t < 8; ++t) {
        v[t] = row[t * 64 + lane];
        s += v[t]; sq += v[t] * v[t];
    }
    s = waveReduceSum(s);
    sq = waveReduceSum(sq);
    float m = s * (1.0f / Dd);
    float var = sq * (1.0f / Dd) - m * m;
    float rs = rsqrtf(var + LN_EPSf);
    _Float16* outp = Ap + (size_t)wid * (2 * Dd);
    #pragma unroll
    for (int t = 0; t < 8; ++t) {
        int d = t * 64 + lane;
        float a = (v[t] - m) * rs * g[d] + b[d];
        _Float16 hi = (_Float16)a;
        outp[d] = hi;
        outp[Dd + d] = (_Float16)(a - (float)hi);
    }
}

// fp32 [rows,K] -> fp16 [rows, 2K] split hi|lo
__global__ __launch_bounds__(256) void pack_split_kernel(
    const float* __restrict__ src, _Float16* __restrict__ dst, int kbits, int total) {
    int idx = blockIdx.x * 256 + threadIdx.x;
    if (idx >= total) return;
    int K = 1 << kbits;
    int row = idx >> kbits, k = idx & (K - 1);
    float v = src[idx];
    _Float16 hi = (_Float16)v;
    _Float16* d = dst + ((size_t)row << (kbits + 1));
    d[k] = hi;
    d[K + k] = (_Float16)(v - (float)hi);
}

// fp32 weight [rows,K] -> fp16 [rows, 2K] duplicated
__global__ __launch_bounds__(256) void pack_wdup_kernel(
    const float* __restrict__ src, _Float16* __restrict__ dst, int kbits, int total) {
    int idx = blockIdx.x * 256 + threadIdx.x;
    if (idx >= total) return;
    int K = 1 << kbits;
    int row = idx >> kbits, k = idx & (K - 1);
    _Float16 h = (_Float16)src[idx];
    _Float16* d = dst + ((size_t)row << (kbits + 1));
    d[k] = h;
    d[K + k] = h;
}

__global__ __launch_bounds__(256) void biaskv_kernel(
    const float* __restrict__ kb, const float* __restrict__ vb, float* __restrict__ dst) {
    int i = blockIdx.x * 256 + threadIdx.x;
    if (i < 512) dst[i] = kb[i];
    else if (i < 1024) dst[i] = vb[i - 512];
}

__global__ __launch_bounds__(256) void slots_init_kernel(
    const float* __restrict__ noise, const float* __restrict__ mu,
    const float* __restrict__ ls, float* __restrict__ slots) {
    int idx = blockIdx.x * 256 + threadIdx.x;
    if (idx >= Bb * NS * Dd) return;
    int d = idx & (Dd - 1);
    slots[idx] = mu[d] + expf(ls[d]) * noise[idx];
}

// ---------------- MFMA GEMM core: 128x128 tile, BK=64, f16, 4 waves ----------------
__device__ __forceinline__ void hgemm_core(
    const _Float16* __restrict__ A, const _Float16* __restrict__ Bw,
    int K2, f32x4 acc[4][4]) {
    __shared__ _Float16 As[128 * 64];
    __shared__ _Float16 Bs[128 * 64];
    const int tid = threadIdx.x;
    const int w = tid >> 6, lane = tid & 63;
    const int r8 = lane >> 3, seg = lane & 7;
    const int lr = lane & 15, quad = lane >> 4;
    const int wm = w >> 1, wn = w & 1;
    for (int k0 = 0; k0 < K2; k0 += 64) {
        __syncthreads();
        #pragma unroll
        for (int g = 0; g < 4; ++g) {
            int grp = w * 4 + g;          // 0..15 row-groups of 8
            int row = grp * 8 + r8;       // 0..127
            async_copy16(A + (size_t)row * K2 + k0 + seg * 8, As + grp * 512);
            async_copy16(Bw + (size_t)row * K2 + k0 + seg * 8, Bs + grp * 512);
        }
        __syncthreads();
        #pragma unroll
        for (int kk = 0; kk < 2; ++kk) {
            half8 a[4], b[4];
            #pragma unroll
            for (int t = 0; t < 4; ++t) {
                a[t] = *(const half8*)(As + (wm * 64 + t * 16 + lr) * 64 + kk * 32 + quad * 8);
                b[t] = *(const half8*)(Bs + (wn * 64 + t * 16 + lr) * 64 + kk * 32 + quad * 8);
            }
            #pragma unroll
            for (int mt = 0; mt < 4; ++mt)
                #pragma unroll
                for (int nt = 0; nt < 4; ++nt)
                    acc[mt][nt] = __builtin_amdgcn_mfma_f32_16x16x32_f16(
                        a[mt], b[nt], acc[mt][nt], 0, 0, 0);
        }
    }
}

template <int ACT>
__device__ __forceinline__ void epilogue_store(
    f32x4 acc[4][4], const float* __restrict__ bias, float* __restrict__ C, int ldc) {
    const int tid = threadIdx.x;
    const int w = tid >> 6, lane = tid & 63;
    const int lr = lane & 15, quad = lane >> 4;
    const int wm = w >> 1, wn = w & 1;
    #pragma unroll
    for (int mt = 0; mt < 4; ++mt)
        #pragma unroll
        for (int nt = 0; nt < 4; ++nt) {
            int m = wm * 64 + mt * 16 + quad * 4;
            int n = wn * 64 + nt * 16 + lr;
            float bv = bias[n];
            #pragma unroll
            for (int r = 0; r < 4; ++r) {
                float val = acc[mt][nt][r] + bv;
                if (ACT) val = gelu_exact(val);
                C[(size_t)(m + r) * ldc + n] = val;
            }
        }
}

template <int ACT>
__global__ __launch_bounds__(256) void hgemm_kernel(
    const _Float16* __restrict__ A, const _Float16* __restrict__ Bw,
    const float* __restrict__ bias, float* __restrict__ C, int K2, int ldc) {
    const int m0 = blockIdx.y * 128, n0 = blockIdx.x * 128;
    f32x4 acc[4][4];
    #pragma unroll
    for (int i = 0; i < 4; ++i)
        #pragma unroll
        for (int j = 0; j < 4; ++j) acc[i][j] = (f32x4){0.f, 0.f, 0.f, 0.f};
    hgemm_core(A + (size_t)m0 * K2, Bw + (size_t)n0 * K2, K2, acc);
    epilogue_store<ACT>(acc, bias + n0, C + (size_t)m0 * ldc + n0, ldc);
}

// kv projection: n<512 -> khalf (fp16), else vbuf (fp32)
__global__ __launch_bounds__(256) void kv_hgemm_kernel(
    const _Float16* __restrict__ A, const _Float16* __restrict__ Bw,
    const float* __restrict__ biaskv, _Float16* __restrict__ khalf,
    float* __restrict__ vbuf) {
    const int m0 = blockIdx.y * 128, n0 = blockIdx.x * 128;
    f32x4 acc[4][4];
    #pragma unroll
    for (int i = 0; i < 4; ++i)
        #pragma unroll
        for (int j = 0; j < 4; ++j) acc[i][j] = (f32x4){0.f, 0.f, 0.f, 0.f};
    hgemm_core(A + (size_t)m0 * 1024, Bw + (size_t)n0 * 1024, 1024, acc);
    const int tid = threadIdx.x;
    const int w = tid >> 6, lane = tid & 63;
    const int lr = lane & 15, quad = lane >> 4;
    const int wm = w >> 1, wn = w & 1;
    #pragma unroll
    for (int mt = 0; mt < 4; ++mt)
        #pragma unroll
        for (int nt = 0; nt < 4; ++nt) {
            int m = m0 + wm * 64 + mt * 16 + quad * 4;
            int n = n0 + wn * 64 + nt * 16 + lr;
            float bv = biaskv[n];
            #pragma unroll
            for (int r = 0; r < 4; ++r) {
                float val = acc[mt][nt][r] + bv;
                if (n < 512) khalf[(size_t)(m + r) * 512 + n] = (_Float16)val;
                else vbuf[(size_t)(m + r) * 512 + (n - 512)] = val;
            }
        }
}

// GRU gemms fused: by<2 -> gi = u@w_ih^T, else gh = slots@w_hh^T (A2 = [upack; slotspack])
__global__ __launch_bounds__(256) void gru_gemm_kernel(
    const _Float16* __restrict__ A2, const _Float16* __restrict__ Bih,
    const _Float16* __restrict__ Bhh, const float* __restrict__ b_ih,
    const float* __restrict__ b_hh, float* __restrict__ gi, float* __restrict__ gh) {
    const int by = blockIdx.y;
    const int n0 = blockIdx.x * 128;
    const int arow = by * 128;
    const _Float16* Bw; const float* bias; float* C; int m0;
    if (by < 2) { Bw = Bih; bias = b_ih; C = gi; m0 = arow; }
    else        { Bw = Bhh; bias = b_hh; C = gh; m0 = arow - 256; }
    f32x4 acc[4][4];
    #pragma unroll
    for (int i = 0; i < 4; ++i)
        #pragma unroll
        for (int j = 0; j < 4; ++j) acc[i][j] = (f32x4){0.f, 0.f, 0.f, 0.f};
    hgemm_core(A2 + (size_t)arow * 1024, Bw + (size_t)n0 * 1024, 1024, acc);
    epilogue_store<0>(acc, bias + n0, C + (size_t)m0 * 1536 + n0, 1536);
}

// ---------------- slot-side elementwise kernels (fp32) ----------------
__global__ __launch_bounds__(256) void ln_apply_kernel(
    const float* __restrict__ x, float* __restrict__ y,
    const float* __restrict__ g, const float* __restrict__ b, int rows) {
    int wid = blockIdx.x * 4 + (threadIdx.x >> 6);
    int lane = threadIdx.x & 63;
    if (wid >= rows) return;
    const float* row = x + (size_t)wid * Dd;
    float v[8];
    float s = 0.f, sq = 0.f;
    #pragma unroll
    for (int t = 0; t < 8; ++t) {
        v[t] = row[t * 64 + lane];
        s += v[t]; sq += v[t] * v[t];
    }
    s = waveReduceSum(s);
    sq = waveReduceSum(sq);
    float m = s * (1.0f / Dd);
    float var = sq * (1.0f / Dd) - m * m;
    float rs = rsqrtf(var + LN_EPSf);
    float* out = y + (size_t)wid * Dd;
    #pragma unroll
    for (int t = 0; t < 8; ++t) {
        int d = t * 64 + lane;
        out[d] = (v[t] - m) * rs * g[d] + b[d];
    }
}

__global__ __launch_bounds__(256) void dots_kernel(
    const float* __restrict__ q, const _Float16* __restrict__ khalf, float* __restrict__ dotsT) {
    const int b = blockIdx.y;
    const int chunk = blockIdx.x;
    __shared__ float qs[NS * Dd];
    const int tid = threadIdx.x;
    const float4* q4 = (const float4*)(q + (size_t)b * NS * Dd);
    float4* qs4 = (float4*)qs;
    #pragma unroll
    for (int p = 0; p < 4; ++p) qs4[tid + p * 256] = q4[tid + p * 256];
    __syncthreads();
    const int wave = tid >> 6, lane = tid & 63;
    for (int t = 0; t < 16; ++t) {
        int j = chunk * 64 + wave * 16 + t;
        const _Float16* krow = khalf + ((size_t)b * Nn + j) * Dd;
        float acc[NS] = {};
        #pragma unroll
        for (int seg = 0; seg < 8; ++seg) {
            float kv = (float)krow[seg * 64 + lane];
            #pragma unroll
            for (int i = 0; i < NS; ++i) acc[i] += qs[i * Dd + seg * 64 + lane] * kv;
        }
        float res = 0.f;
        #pragma unroll
        for (int i = 0; i < NS; ++i) {
            float v = acc[i];
            #pragma unroll
            for (int m = 32; m >= 1; m >>= 1) v += __shfl_xor(v, m);
            if (lane == i) res = v;
        }
        if (lane < NS) dotsT[((size_t)b * Nn + j) * NS + lane] = res * SCALEf;
    }
}

__global__ __launch_bounds__(256) void softmax_kernel(
    float* __restrict__ att, float* __restrict__ sums) {
    int idx = blockIdx.x * 256 + threadIdx.x;  // one per (b, j)
    int b = idx >> 11;
    float4 x0 = ((float4*)att)[idx * 2];
    float4 x1 = ((float4*)att)[idx * 2 + 1];
    float v[8] = {x0.x, x0.y, x0.z, x0.w, x1.x, x1.y, x1.z, x1.w};
    float m = v[0];
    #pragma unroll
    for (int i = 1; i < 8; ++i) m = fmaxf(m, v[i]);
    float s = 0.f;
    #pragma unroll
    for (int i = 0; i < 8; ++i) { v[i] = expf(v[i] - m); s += v[i]; }
    float inv = 1.0f / s;
    #pragma unroll
    for (int i = 0; i < 8; ++i) v[i] = v[i] * inv + EPSf;
    float4 o0 = {v[0], v[1], v[2], v[3]};
    float4 o1 = {v[4], v[5], v[6], v[7]};
    ((float4*)att)[idx * 2] = o0;
    ((float4*)att)[idx * 2 + 1] = o1;
    int lane = threadIdx.x & 63;
    #pragma unroll
    for (int i = 0; i < 8; ++i) {
        float t = waveReduceSum(v[i]);
        if (lane == 0) atomicAdd(&sums[b * NS + i], t);
    }
}

__global__ __launch_bounds__(256) void updates_kernel(
    const float* __restrict__ att, const float* __restrict__ v, float* __restrict__ raw) {
    const int b = blockIdx.y;
    const int jc = blockIdx.x;
    const int tid = threadIdx.x;
    __shared__ float asm_[64 * NS];
    float2 acc[NS];
    #pragma unroll
    for (int i = 0; i < NS; ++i) { acc[i].x = 0.f; acc[i].y = 0.f; }
    for (int g = 0; g < 2; ++g) {
        int j0 = jc * 128 + g * 64;
        __syncthreads();
        ((float2*)asm_)[tid] = ((const float2*)(att + ((size_t)b * Nn + j0) * NS))[tid];
        __syncthreads();
        for (int jl = 0; jl < 64; ++jl) {
            float2 vv = *(const float2*)(v + ((size_t)b * Nn + j0 + jl) * Dd + tid * 2);
            #pragma unroll
            for (int i = 0; i < NS; ++i) {
                float a = asm_[jl * NS + i];
                acc[i].x += a * vv.x;
                acc[i].y += a * vv.y;
            }
        }
    }
    #pragma unroll
    for (int i = 0; i < NS; ++i) {
        float* p = raw + ((size_t)(b * NS + i)) * Dd + tid * 2;
        atomicAdd(p, acc[i].x);
        atomicAdd(p + 1, acc[i].y);
    }
}

__global__ __launch_bounds__(256) void finalize_kernel(
    const float* __restrict__ raw, const float* __restrict__ sums,
    float* __restrict__ u, float* __restrict__ out0) {
    int idx = blockIdx.x * 256 + threadIdx.x;
    if (idx >= Bb * NS * Dd) return;
    int row = idx >> 9;
    float val = raw[idx] / sums[row];
    u[idx] = val;
    out0[idx] = val;
}

__global__ __launch_bounds__(256) void gru_elem_kernel(
    const float* __restrict__ gi, const float* __restrict__ gh,
    const float* __restrict__ u, float* __restrict__ slots) {
    int idx = blockIdx.x * 256 + threadIdx.x;
    if (idx >= Bb * NS * Dd) return;
    int row = idx >> 9, d = idx & (Dd - 1);
    const float* gir = gi + (size_t)row * 1536;
    const float* ghr = gh + (size_t)row * 1536;
    float ir = gir[d], iz = gir[512 + d], in_ = gir[1024 + d];
    float hr = ghr[d], hz = ghr[512 + d], hn = ghr[1024 + d];
    float r = 1.0f / (1.0f + expf(-(ir + hr)));
    float z = 1.0f / (1.0f + expf(-(iz + hz)));
    float n = tanhf(in_ + r * hn);
    float h = slots[idx];
    float hnew = (1.0f - z) * n + z * h;
    slots[idx] = u[idx] + hnew;
}

// ---------------- launch ----------------
extern "C" void kernel_launch(void* const* d_in, const int* in_sizes, int n_in,
                              void* d_out, int out_size, void* d_ws, size_t ws_size,
                              hipStream_t stream) {
    const float* inputs   = (const float*)d_in[0];
    const float* noise    = (const float*)d_in[1];
    const float* mu       = (const float*)d_in[2];
    const float* lsig     = (const float*)d_in[3];
    const float* k_w      = (const float*)d_in[4];
    const float* k_b      = (const float*)d_in[5];
    const float* v_w      = (const float*)d_in[6];
    const float* v_b      = (const float*)d_in[7];
    const float* w_ih     = (const float*)d_in[8];
    const float* w_hh     = (const float*)d_in[9];
    const float* b_ih     = (const float*)d_in[10];
    const float* b_hh     = (const float*)d_in[11];
    const float* ln_in_g  = (const float*)d_in[12];
    const float* ln_in_b  = (const float*)d_in[13];
    const float* ln_s_g   = (const float*)d_in[14];
    const float* ln_s_b   = (const float*)d_in[15];
    const float* ln_p_g   = (const float*)d_in[16];
    const float* ln_p_b   = (const float*)d_in[17];
    const float* mlp1_w   = (const float*)d_in[18];
    const float* mlp1_b   = (const float*)d_in[19];
    const float* mlp2_w   = (const float*)d_in[20];
    const float* mlp2_b   = (const float*)d_in[21];
    const float* mlp3_w   = (const float*)d_in[22];
    const float* mlp3_b   = (const float*)d_in[23];
    const float* mlp4_w   = (const float*)d_in[24];
    const float* mlp4_b   = (const float*)d_in[25];
    float* out0 = (float*)d_out;                 // updates [32,8,512]
    float* out1 = (float*)d_out + Bb * NS * Dd;  // s [32,8,256]

    char* wp = (char*)d_ws;
    auto alloc = [&](size_t bytes) -> void* {
        void* p = (void*)wp;
        wp += (bytes + 255) & ~(size_t)255;
        return p;
    };
    const size_t MR = (size_t)Bb * Nn;  // 65536
    _Float16* Apack = (_Float16*)alloc(MR * 1024 * 2);          // 134 MB
    _Float16* khalf = (_Float16*)alloc(MR * 512 * 2);           // 67 MB
    float*    vbuf  = (float*)alloc(MR * 512 * 4);              // 134 MB
    _Float16* Bkv   = (_Float16*)alloc((size_t)1024 * 1024 * 2);
    _Float16* Bih   = (_Float16*)alloc((size_t)1536 * 1024 * 2);
    _Float16* Bhh   = (_Float16*)alloc((size_t)1536 * 1024 * 2);
    _Float16* Bm1   = (_Float16*)alloc((size_t)1024 * 1024 * 2);
    _Float16* Bm2   = (_Float16*)alloc((size_t)1024 * 2048 * 2);
    _Float16* Bm3   = (_Float16*)alloc((size_t)512 * 2048 * 2);
    _Float16* Bm4   = (_Float16*)alloc((size_t)256 * 1024 * 2);
    float* biaskv   = (float*)alloc(1024 * 4);
    float* slots    = (float*)alloc((size_t)Bb * NS * Dd * 4);
    float* qbuf     = (float*)alloc((size_t)Bb * NS * Dd * 4);
    float* att      = (float*)alloc((size_t)Bb * Nn * NS * 4);
    float* sums     = (float*)alloc((size_t)Bb * NS * 4);
    float* raw      = (float*)alloc((size_t)Bb * NS * Dd * 4);
    float* ubuf     = (float*)alloc((size_t)Bb * NS * Dd * 4);
    float* gi       = (float*)alloc((size_t)Bb * NS * 1536 * 4);
    float* gh       = (float*)alloc((size_t)Bb * NS * 1536 * 4);
    _Float16* A2    = (_Float16*)alloc((size_t)512 * 1024 * 2);
    float* sln      = (float*)alloc((size_t)Bb * NS * Dd * 4);
    _Float16* P1    = (_Float16*)alloc((size_t)256 * 1024 * 2);
    _Float16* P2    = (_Float16*)alloc((size_t)256 * 2048 * 2);
    _Float16* P3    = (_Float16*)alloc((size_t)256 * 2048 * 2);
    _Float16* P4    = (_Float16*)alloc((size_t)256 * 1024 * 2);
    float* h1       = (float*)alloc((size_t)256 * 1024 * 4);
    float* h2       = (float*)alloc((size_t)256 * 1024 * 4);
    float* h3       = (float*)alloc((size_t)256 * 512 * 4);

    // ---- pack phase ----
    pack_ln_split_kernel<<<MR / 4, 256, 0, stream>>>(inputs, ln_in_g, ln_in_b, Apack);
    pack_wdup_kernel<<<1024, 256, 0, stream>>>(k_w, Bkv, 9, 512 * 512);
    pack_wdup_kernel<<<1024, 256, 0, stream>>>(v_w, Bkv + (size_t)512 * 1024, 9, 512 * 512);
    pack_wdup_kernel<<<3072, 256, 0, stream>>>(w_ih, Bih, 9, 1536 * 512);
    pack_wdup_kernel<<<3072, 256, 0, stream>>>(w_hh, Bhh, 9, 1536 * 512);
    pack_wdup_kernel<<<2048, 256, 0, stream>>>(mlp1_w, Bm1, 9, 1024 * 512);
    pack_wdup_kernel<<<4096, 256, 0, stream>>>(mlp2_w, Bm2, 10, 1024 * 1024);
    pack_wdup_kernel<<<2048, 256, 0, stream>>>(mlp3_w, Bm3, 10, 512 * 1024);
    pack_wdup_kernel<<<512, 256, 0, stream>>>(mlp4_w, Bm4, 9, 256 * 512);
    biaskv_kernel<<<4, 256, 0, stream>>>(k_b, v_b, biaskv);
    slots_init_kernel<<<(Bb * NS * Dd) / 256, 256, 0, stream>>>(noise, mu, lsig, slots);

    // ---- kv projection (MFMA) ----
    kv_hgemm_kernel<<<dim3(8, MR / 128), 256, 0, stream>>>(Apack, Bkv, biaskv, khalf, vbuf);

    for (int it = 0; it < ITERS; ++it) {
        ln_apply_kernel<<<(Bb * NS) / 4, 256, 0, stream>>>(slots, qbuf, ln_s_g, ln_s_b, Bb * NS);
        dots_kernel<<<dim3(32, Bb), 256, 0, stream>>>(qbuf, khalf, att);
        hipMemsetAsync(sums, 0, Bb * NS * 4, stream);
        softmax_kernel<<<(Bb * Nn) / 256, 256, 0, stream>>>(att, sums);
        hipMemsetAsync(raw, 0, (size_t)Bb * NS * Dd * 4, stream);
        updates_kernel<<<dim3(16, Bb), 256, 0, stream>>>(att, vbuf, raw);
        finalize_kernel<<<(Bb * NS * Dd) / 256, 256, 0, stream>>>(raw, sums, ubuf, out0);
        pack_split_kernel<<<512, 256, 0, stream>>>(ubuf, A2, 9, 256 * 512);
        pack_split_kernel<<<512, 256, 0, stream>>>(slots, A2 + (size_t)256 * 1024, 9, 256 * 512);
        gru_gemm_kernel<<<dim3(12, 4), 256, 0, stream>>>(A2, Bih, Bhh, b_ih, b_hh, gi, gh);
        gru_elem_kernel<<<(Bb * NS * Dd) / 256, 256, 0, stream>>>(gi, gh, ubuf, slots);
    }

    // ---- output MLP (MFMA) ----
    ln_apply_kernel<<<(Bb * NS) / 4, 256, 0, stream>>>(slots, sln, ln_p_g, ln_p_b, Bb * NS);
    pack_split_kernel<<<512, 256, 0, stream>>>(sln, P1, 9, 256 * 512);
    hgemm_kernel<1><<<dim3(8, 2), 256, 0, stream>>>(P1, Bm1, mlp1_b, h1, 1024, 1024);
    pack_split_kernel<<<1024, 256, 0, stream>>>(h1, P2, 10, 256 * 1024);
    hgemm_kernel<1><<<dim3(8, 2), 256, 0, stream>>>(P2, Bm2, mlp2_b, h2, 2048, 1024);
    pack_split_kernel<<<1024, 256, 0, stream>>>(h2, P3, 10, 256 * 1024);
    hgemm_kernel<1><<<dim3(4, 2), 256, 0, stream>>>(P3, Bm3, mlp3_b, h3, 2048, 512);
    pack_split_kernel<<<512, 256, 0, stream>>>(h3, P4, 9, 256 * 512);
    hgemm_kernel<0><<<dim3(2, 2), 256, 0, stream>>>(P4, Bm4, mlp4_b, out1, 1024, 256);
}

// Round 3
// 664.378 us; speedup vs baseline: 2.7038x; 1.6414x over previous
//
#include <hip/hip_runtime.h>
#include <math.h>

#define Bb 32
#define Nn 2048
#define Dd 512
#define NS 8
#define ITERS 3
#define EPSf 1e-8f
#define SCALEf 0.04419417382415922f   // 512^-0.5
#define LN_EPSf 1e-5f

#define QHS 520    // qh LDS row stride (halves) - padded vs bank conflicts
#define PTS 136    // pT LDS row stride (halves)

typedef _Float16 half8 __attribute__((ext_vector_type(8)));
typedef float f32x4 __attribute__((ext_vector_type(4)));

__device__ __forceinline__ float waveReduceSum(float v) {
    #pragma unroll
    for (int m = 32; m >= 1; m >>= 1) v += __shfl_xor(v, m);
    return v;
}

__device__ __forceinline__ float gelu_exact(float x) {
    return 0.5f * x * (1.0f + erff(x * 0.7071067811865476f));
}

__device__ __forceinline__ void async_copy16(const _Float16* g, _Float16* l) {
    __builtin_amdgcn_global_load_lds(
        (const __attribute__((address_space(1))) unsigned int*)g,
        (__attribute__((address_space(3))) unsigned int*)l, 16, 0, 0);
}

// ================= pack kernels =================
// all weights -> fp16 in one launch. kv plain [1024][512]; others dup hi==lo [N][2K].
__global__ __launch_bounds__(256) void megapack_kernel(
    const float* __restrict__ k_w, const float* __restrict__ v_w,
    const float* __restrict__ w_ih, const float* __restrict__ w_hh,
    const float* __restrict__ m1, const float* __restrict__ m2,
    const float* __restrict__ m3, const float* __restrict__ m4,
    _Float16* __restrict__ Bkv, _Float16* __restrict__ Bih, _Float16* __restrict__ Bhh,
    _Float16* __restrict__ Bm1, _Float16* __restrict__ Bm2,
    _Float16* __restrict__ Bm3, _Float16* __restrict__ Bm4) {
    int bid = blockIdx.x, tid = threadIdx.x;
    const float* src; _Float16* dst; int kbits, base;
    if (bid < 2048) {   // kv plain copy
        int i = bid * 256 + tid;
        Bkv[i] = (_Float16)(i < 262144 ? k_w[i] : v_w[i - 262144]);
        return;
    }
    else if (bid < 5120)  { src = w_ih; dst = Bih; kbits = 9;  base = 2048; }
    else if (bid < 8192)  { src = w_hh; dst = Bhh; kbits = 9;  base = 5120; }
    else if (bid < 10240) { src = m1;   dst = Bm1; kbits = 9;  base = 8192; }
    else if (bid < 14336) { src = m2;   dst = Bm2; kbits = 10; base = 10240; }
    else if (bid < 16384) { src = m3;   dst = Bm3; kbits = 10; base = 14336; }
    else                  { src = m4;   dst = Bm4; kbits = 9;  base = 16384; }
    int e = (bid - base) * 256 + tid;
    int K = 1 << kbits;
    int row = e >> kbits, k = e & (K - 1);
    _Float16 h = (_Float16)src[e];
    _Float16* d = dst + ((size_t)row << (kbits + 1));
    d[k] = h;
    d[K + k] = h;
}

// LN(inputs) -> Apack fp16 [65536][512] (single precision A for kv gemm)
__global__ __launch_bounds__(256) void pack_ln_single_kernel(
    const float* __restrict__ x, const float* __restrict__ g, const float* __restrict__ b,
    _Float16* __restrict__ Ap) {
    int wid = blockIdx.x * 4 + (threadIdx.x >> 6);
    int lane = threadIdx.x & 63;
    const float* row = x + (size_t)wid * Dd;
    float v[8];
    float s = 0.f, sq = 0.f;
    #pragma unroll
    for (int t = 0; t < 8; ++t) {
        v[t] = row[t * 64 + lane];
        s += v[t]; sq += v[t] * v[t];
    }
    s = waveReduceSum(s);
    sq = waveReduceSum(sq);
    float m = s * (1.0f / Dd);
    float var = sq * (1.0f / Dd) - m * m;
    float rs = rsqrtf(var + LN_EPSf);
    _Float16* outp = Ap + (size_t)wid * Dd;
    #pragma unroll
    for (int t = 0; t < 8; ++t) {
        int d = t * 64 + lane;
        outp[d] = (_Float16)((v[t] - m) * rs * g[d] + b[d]);
    }
}

// slots init (fp32) + pack into A2 slot-half (rows 256..511, hi|lo)
__global__ __launch_bounds__(256) void slots_init_kernel(
    const float* __restrict__ noise, const float* __restrict__ mu,
    const float* __restrict__ ls, float* __restrict__ slots, _Float16* __restrict__ A2) {
    int idx = blockIdx.x * 256 + threadIdx.x;
    if (idx >= Bb * NS * Dd) return;
    int d = idx & (Dd - 1);
    float val = mu[d] + expf(ls[d]) * noise[idx];
    slots[idx] = val;
    int row = idx >> 9;
    _Float16 hi = (_Float16)val;
    A2[(size_t)(256 + row) * 1024 + d] = hi;
    A2[(size_t)(256 + row) * 1024 + 512 + d] = (_Float16)(val - (float)hi);
}

// ================= 128-tile MFMA core (kv) =================
__device__ __forceinline__ void hgemm128_core(
    const _Float16* __restrict__ A, const _Float16* __restrict__ Bw,
    int K2, f32x4 acc[4][4], _Float16* As, _Float16* Bs) {
    const int tid = threadIdx.x;
    const int w = tid >> 6, lane = tid & 63;
    const int r8 = lane >> 3, seg = lane & 7;
    const int lr = lane & 15, quad = lane >> 4;
    const int wm = w >> 1, wn = w & 1;
    for (int k0 = 0; k0 < K2; k0 += 64) {
        __syncthreads();
        #pragma unroll
        for (int g = 0; g < 4; ++g) {
            int grp = w * 4 + g;
            int row = grp * 8 + r8;
            async_copy16(A + (size_t)row * K2 + k0 + seg * 8, As + grp * 512);
            async_copy16(Bw + (size_t)row * K2 + k0 + seg * 8, Bs + grp * 512);
        }
        __syncthreads();
        #pragma unroll
        for (int kk = 0; kk < 2; ++kk) {
            half8 a[4], b[4];
            #pragma unroll
            for (int t = 0; t < 4; ++t) {
                a[t] = *(const half8*)(As + (wm * 64 + t * 16 + lr) * 64 + kk * 32 + quad * 8);
                b[t] = *(const half8*)(Bs + (wn * 64 + t * 16 + lr) * 64 + kk * 32 + quad * 8);
            }
            #pragma unroll
            for (int mt = 0; mt < 4; ++mt)
                #pragma unroll
                for (int nt = 0; nt < 4; ++nt)
                    acc[mt][nt] = __builtin_amdgcn_mfma_f32_16x16x32_f16(
                        a[mt], b[nt], acc[mt][nt], 0, 0, 0);
        }
    }
}

// kv projection: A single fp16 K=512. n0<512 -> khalf [tok][512]; else vT [b][d][tok].
// Outputs staged through LDS for coalesced fp16 writes.
__global__ __launch_bounds__(256) void kv_hgemm_kernel(
    const _Float16* __restrict__ Apack, const _Float16* __restrict__ Bkv,
    const float* __restrict__ k_b, const float* __restrict__ v_b,
    _Float16* __restrict__ khalf, _Float16* __restrict__ vT) {
    __shared__ _Float16 smem[17408];   // As[8192] | Bs[8192], reused as Ct[128][136]
    _Float16* As = smem;
    _Float16* Bs = smem + 8192;
    const int m0 = blockIdx.y * 128, n0 = blockIdx.x * 128;
    f32x4 acc[4][4];
    #pragma unroll
    for (int i = 0; i < 4; ++i)
        #pragma unroll
        for (int j = 0; j < 4; ++j) acc[i][j] = (f32x4){0.f, 0.f, 0.f, 0.f};
    hgemm128_core(Apack + (size_t)m0 * 512, Bkv + (size_t)n0 * 512, 512, acc, As, Bs);
    __syncthreads();
    const int tid = threadIdx.x;
    const int w = tid >> 6, lane = tid & 63;
    const int lr = lane & 15, quad = lane >> 4;
    const int wm = w >> 1, wn = w & 1;
    const bool isK = (n0 < 512);
    #pragma unroll
    for (int mt = 0; mt < 4; ++mt)
        #pragma unroll
        for (int nt = 0; nt < 4; ++nt) {
            int ml = wm * 64 + mt * 16 + quad * 4;
            int nl = wn * 64 + nt * 16 + lr;
            float bv = isK ? k_b[n0 + nl] : v_b[n0 - 512 + nl];
            #pragma unroll
            for (int r = 0; r < 4; ++r) {
                _Float16 h = (_Float16)(acc[mt][nt][r] + bv);
                if (isK) smem[(ml + r) * 136 + nl] = h;    // [token][d]
                else     smem[nl * 136 + ml + r] = h;      // [d][token]
            }
        }
    __syncthreads();
    int r = tid >> 1, half = tid & 1;
    _Float16* dst;
    if (isK) {
        dst = khalf + (size_t)(m0 + r) * 512 + n0 + half * 64;
    } else {
        int b = m0 >> 11, j0 = m0 & 2047, d0 = n0 - 512;
        dst = vT + ((size_t)b * 512 + d0 + r) * 2048 + j0 + half * 64;
    }
    #pragma unroll
    for (int c = 0; c < 8; ++c)
        *(half8*)(dst + c * 8) = *(const half8*)(smem + r * 136 + half * 64 + c * 8);
}

// ================= fused attention iteration =================
// per block: LN(slots[b]) -> qh; QK^T (MFMA) -> slot-softmax -> +EPS;
// P.V (MFMA) -> partial raw/sums per chunk.
__global__ __launch_bounds__(256) void attn_kernel(
    const float* __restrict__ slots, const float* __restrict__ ln_g, const float* __restrict__ ln_b,
    const _Float16* __restrict__ khalf, const _Float16* __restrict__ vT,
    float* __restrict__ rawp, float* __restrict__ sumsp) {
    const int b = blockIdx.y, chunk = blockIdx.x;
    __shared__ _Float16 qh[16 * QHS];
    __shared__ _Float16 pT[16 * PTS];
    __shared__ float sums_lds[64];
    const int tid = threadIdx.x, w = tid >> 6, lane = tid & 63;
    const int lr = lane & 15, quad = lane >> 4;

    // LN + scale + fp16 pack of q (8 rows), zero-pad rows 8..15
    #pragma unroll
    for (int rr = 0; rr < 2; ++rr) {
        int row = w * 2 + rr;
        const float* sr = slots + ((size_t)b * NS + row) * Dd;
        float v[8]; float s = 0.f, sq = 0.f;
        #pragma unroll
        for (int t = 0; t < 8; ++t) {
            v[t] = sr[t * 64 + lane];
            s += v[t]; sq += v[t] * v[t];
        }
        s = waveReduceSum(s);
        sq = waveReduceSum(sq);
        float m = s * (1.0f / Dd);
        float var = sq * (1.0f / Dd) - m * m;
        float rs = rsqrtf(var + LN_EPSf);
        #pragma unroll
        for (int t = 0; t < 8; ++t) {
            int d = t * 64 + lane;
            qh[row * QHS + d] = (_Float16)(((v[t] - m) * rs * ln_g[d] + ln_b[d]) * SCALEf);
            qh[(row + 8) * QHS + d] = (_Float16)0.f;
        }
    }
    __syncthreads();

    // QK: wave handles 32 tokens; A=k rows (m=token), B=qh (n=slot)
    const int j0 = chunk * 128 + w * 32;
    f32x4 dots[2];
    dots[0] = (f32x4){0.f, 0.f, 0.f, 0.f};
    dots[1] = (f32x4){0.f, 0.f, 0.f, 0.f};
    for (int ks = 0; ks < 16; ++ks) {
        half8 bq = *(const half8*)(qh + lr * QHS + ks * 32 + quad * 8);
        #pragma unroll
        for (int mf = 0; mf < 2; ++mf) {
            half8 ak = *(const half8*)(khalf + ((size_t)b * Nn + j0 + mf * 16 + lr) * 512 + ks * 32 + quad * 8);
            dots[mf] = __builtin_amdgcn_mfma_f32_16x16x32_f16(ak, bq, dots[mf], 0, 0, 0);
        }
    }
    // softmax over slots (cols = lanes 0..7 within 8-lane group)
    float ssum = 0.f;
    #pragma unroll
    for (int mf = 0; mf < 2; ++mf) {
        f32x4 d = dots[mf];
        f32x4 mx = d;
        #pragma unroll
        for (int msk = 1; msk <= 4; msk <<= 1) {
            #pragma unroll
            for (int r = 0; r < 4; ++r) mx[r] = fmaxf(mx[r], __shfl_xor(mx[r], msk));
        }
        f32x4 p;
        #pragma unroll
        for (int r = 0; r < 4; ++r) p[r] = __expf(d[r] - mx[r]);
        f32x4 sm = p;
        #pragma unroll
        for (int msk = 1; msk <= 4; msk <<= 1) {
            #pragma unroll
            for (int r = 0; r < 4; ++r) sm[r] += __shfl_xor(sm[r], msk);
        }
        #pragma unroll
        for (int r = 0; r < 4; ++r) {
            _Float16 ph = (_Float16)(p[r] / sm[r] + EPSf);
            pT[lr * PTS + w * 32 + mf * 16 + quad * 4 + r] = ph;
            ssum += (float)ph;
        }
    }
    ssum += __shfl_xor(ssum, 16);
    ssum += __shfl_xor(ssum, 32);
    if (lane < 16) sums_lds[w * 16 + lane] = ssum;
    __syncthreads();

    // PV: A = P^T (m=slot), B = vT (n=d); wave covers d-range w*128
    f32x4 acc[8];
    #pragma unroll
    for (int nf = 0; nf < 8; ++nf) acc[nf] = (f32x4){0.f, 0.f, 0.f, 0.f};
    #pragma unroll
    for (int kc = 0; kc < 4; ++kc) {
        half8 ap = *(const half8*)(pT + lr * PTS + kc * 32 + quad * 8);
        #pragma unroll
        for (int nf = 0; nf < 8; ++nf) {
            int dcol = w * 128 + nf * 16 + lr;
            half8 bv = *(const half8*)(vT + ((size_t)b * 512 + dcol) * 2048 + chunk * 128 + kc * 32 + quad * 8);
            acc[nf] = __builtin_amdgcn_mfma_f32_16x16x32_f16(ap, bv, acc[nf], 0, 0, 0);
        }
    }
    // partial raw: rows=slots (quads 0,1 hold slots 0..7)
    if (quad < 2) {
        #pragma unroll
        for (int nf = 0; nf < 8; ++nf) {
            #pragma unroll
            for (int r = 0; r < 4; ++r) {
                int slot = quad * 4 + r;
                rawp[(((size_t)chunk * Bb + b) * NS + slot) * Dd + w * 128 + nf * 16 + lr] = acc[nf][r];
            }
        }
    }
    if (w == 0 && lane < NS) {
        float tot = sums_lds[lane] + sums_lds[16 + lane] + sums_lds[32 + lane] + sums_lds[48 + lane];
        sumsp[((size_t)chunk * Bb + b) * NS + lane] = tot;
    }
}

// finalize: u = sum_c rawp / sum_c sumsp ; write ubuf, out0, and A2 u-rows (hi|lo)
__global__ __launch_bounds__(256) void finalize_kernel(
    const float* __restrict__ rawp, const float* __restrict__ sumsp,
    float* __restrict__ u, float* __restrict__ out0, _Float16* __restrict__ A2) {
    int idx = blockIdx.x * 256 + threadIdx.x;   // 131072
    int row = idx >> 9, k = idx & 511;
    float rs = 0.f, ss = 0.f;
    #pragma unroll
    for (int c = 0; c < 16; ++c) {
        rs += rawp[(size_t)c * 131072 + idx];
        ss += sumsp[c * 256 + row];
    }
    float val = rs / ss;
    u[idx] = val;
    out0[idx] = val;
    _Float16 hi = (_Float16)val;
    A2[(size_t)row * 1024 + k] = hi;
    A2[(size_t)row * 1024 + 512 + k] = (_Float16)(val - (float)hi);
}

// ================= 64-tile MFMA core (small gemms) =================
__device__ __forceinline__ void hgemm64_core(
    const _Float16* __restrict__ A, const _Float16* __restrict__ Bw,
    int K2, f32x4 acc[2][2], _Float16* As, _Float16* Bs) {
    const int tid = threadIdx.x;
    const int w = tid >> 6, lane = tid & 63;
    const int r8 = lane >> 3, seg = lane & 7;
    const int lr = lane & 15, quad = lane >> 4;
    const int wm = w >> 1, wn = w & 1;
    for (int k0 = 0; k0 < K2; k0 += 64) {
        __syncthreads();
        #pragma unroll
        for (int p = 0; p < 2; ++p) {
            int grp = p * 4 + w;
            int row = grp * 8 + r8;
            async_copy16(A + (size_t)row * K2 + k0 + seg * 8, As + grp * 512);
            async_copy16(Bw + (size_t)row * K2 + k0 + seg * 8, Bs + grp * 512);
        }
        __syncthreads();
        #pragma unroll
        for (int kk = 0; kk < 2; ++kk) {
            half8 a[2], b[2];
            #pragma unroll
            for (int t = 0; t < 2; ++t) {
                a[t] = *(const half8*)(As + (wm * 32 + t * 16 + lr) * 64 + kk * 32 + quad * 8);
                b[t] = *(const half8*)(Bs + (wn * 32 + t * 16 + lr) * 64 + kk * 32 + quad * 8);
            }
            #pragma unroll
            for (int mt = 0; mt < 2; ++mt)
                #pragma unroll
                for (int nt = 0; nt < 2; ++nt)
                    acc[mt][nt] = __builtin_amdgcn_mfma_f32_16x16x32_f16(
                        a[mt], b[nt], acc[mt][nt], 0, 0, 0);
        }
    }
}

// generic 64-tile gemm: C=act(A@Bw^T+bias); PACK -> write next-layer A (hi|lo, width Kp)
template <int ACT, int PACK>
__global__ __launch_bounds__(256) void hgemm64_kernel(
    const _Float16* __restrict__ A, const _Float16* __restrict__ Bw,
    const float* __restrict__ bias, float* __restrict__ C, _Float16* __restrict__ P,
    int K2, int N, int Kp) {
    __shared__ _Float16 As[4096], Bs[4096];
    const int m0 = blockIdx.y * 64, n0 = blockIdx.x * 64;
    f32x4 acc[2][2];
    #pragma unroll
    for (int i = 0; i < 2; ++i)
        #pragma unroll
        for (int j = 0; j < 2; ++j) acc[i][j] = (f32x4){0.f, 0.f, 0.f, 0.f};
    hgemm64_core(A + (size_t)m0 * K2, Bw + (size_t)n0 * K2, K2, acc, As, Bs);
    const int tid = threadIdx.x;
    const int w = tid >> 6, lane = tid & 63;
    const int lr = lane & 15, quad = lane >> 4;
    const int wm = w >> 1, wn = w & 1;
    #pragma unroll
    for (int mt = 0; mt < 2; ++mt)
        #pragma unroll
        for (int nt = 0; nt < 2; ++nt) {
            int n = n0 + wn * 32 + nt * 16 + lr;
            float bv = bias[n];
            #pragma unroll
            for (int r = 0; r < 4; ++r) {
                int m = m0 + wm * 32 + mt * 16 + quad * 4 + r;
                float val = acc[mt][nt][r] + bv;
                if (ACT) val = gelu_exact(val);
                if (PACK) {
                    _Float16 hi = (_Float16)val;
                    P[(size_t)m * 2 * Kp + n] = hi;
                    P[(size_t)m * 2 * Kp + Kp + n] = (_Float16)(val - (float)hi);
                } else {
                    C[(size_t)m * N + n] = val;
                }
            }
        }
}

// GRU gemms: by<4 -> gi = u@w_ih^T (A2 rows 0..255), else gh = slots@w_hh^T (rows 256..511)
__global__ __launch_bounds__(256) void gru_gemm_kernel(
    const _Float16* __restrict__ A2, const _Float16* __restrict__ Bih,
    const _Float16* __restrict__ Bhh, const float* __restrict__ b_ih,
    const float* __restrict__ b_hh, float* __restrict__ gi, float* __restrict__ gh) {
    __shared__ _Float16 As[4096], Bs[4096];
    const int by = blockIdx.y;
    const int n0 = blockIdx.x * 64;
    const _Float16* Ap; const _Float16* Bw; const float* bias; float* C;
    if (by < 4) { Ap = A2 + (size_t)by * 64 * 1024;        Bw = Bih; bias = b_ih; C = gi + (size_t)by * 64 * 1536; }
    else        { Ap = A2 + (size_t)(256 + (by - 4) * 64) * 1024; Bw = Bhh; bias = b_hh; C = gh + (size_t)(by - 4) * 64 * 1536; }
    f32x4 acc[2][2];
    #pragma unroll
    for (int i = 0; i < 2; ++i)
        #pragma unroll
        for (int j = 0; j < 2; ++j) acc[i][j] = (f32x4){0.f, 0.f, 0.f, 0.f};
    hgemm64_core(Ap, Bw + (size_t)n0 * 1024, 1024, acc, As, Bs);
    const int tid = threadIdx.x;
    const int w = tid >> 6, lane = tid & 63;
    const int lr = lane & 15, quad = lane >> 4;
    const int wm = w >> 1, wn = w & 1;
    #pragma unroll
    for (int mt = 0; mt < 2; ++mt)
        #pragma unroll
        for (int nt = 0; nt < 2; ++nt) {
            int n = n0 + wn * 32 + nt * 16 + lr;
            float bv = bias[n];
            #pragma unroll
            for (int r = 0; r < 4; ++r) {
                int m = wm * 32 + mt * 16 + quad * 4 + r;
                C[(size_t)m * 1536 + n] = acc[mt][nt][r] + bv;
            }
        }
}

// GRU elementwise; slots updated in place + A2 slot-rows repacked for next iter
__global__ __launch_bounds__(256) void gru_elem_kernel(
    const float* __restrict__ gi, const float* __restrict__ gh,
    const float* __restrict__ u, float* __restrict__ slots, _Float16* __restrict__ A2) {
    int idx = blockIdx.x * 256 + threadIdx.x;
    if (idx >= Bb * NS * Dd) return;
    int row = idx >> 9, d = idx & (Dd - 1);
    const float* gir = gi + (size_t)row * 1536;
    const float* ghr = gh + (size_t)row * 1536;
    float ir = gir[d], iz = gir[512 + d], in_ = gir[1024 + d];
    float hr = ghr[d], hz = ghr[512 + d], hn = ghr[1024 + d];
    float r = 1.0f / (1.0f + expf(-(ir + hr)));
    float z = 1.0f / (1.0f + expf(-(iz + hz)));
    float n = tanhf(in_ + r * hn);
    float h = slots[idx];
    float hnew = (1.0f - z) * n + z * h;
    float val = u[idx] + hnew;
    slots[idx] = val;
    _Float16 hi = (_Float16)val;
    A2[(size_t)(256 + row) * 1024 + d] = hi;
    A2[(size_t)(256 + row) * 1024 + 512 + d] = (_Float16)(val - (float)hi);
}

// LN(slots) -> P1 hi|lo (rows=256)
__global__ __launch_bounds__(256) void lnpack_kernel(
    const float* __restrict__ x, const float* __restrict__ g, const float* __restrict__ b,
    _Float16* __restrict__ P) {
    int wid = blockIdx.x * 4 + (threadIdx.x >> 6);
    int lane = threadIdx.x & 63;
    const float* row = x + (size_t)wid * Dd;
    float v[8];
    float s = 0.f, sq = 0.f;
    #pragma unroll
    for (int t = 0; t < 8; ++t) {
        v[t] = row[t * 64 + lane];
        s += v[t]; sq += v[t] * v[t];
    }
    s = waveReduceSum(s);
    sq = waveReduceSum(sq);
    float m = s * (1.0f / Dd);
    float var = sq * (1.0f / Dd) - m * m;
    float rs = rsqrtf(var + LN_EPSf);
    _Float16* outp = P + (size_t)wid * 1024;
    #pragma unroll
    for (int t = 0; t < 8; ++t) {
        int d = t * 64 + lane;
        float a = (v[t] - m) * rs * g[d] + b[d];
        _Float16 hi = (_Float16)a;
        outp[d] = hi;
        outp[512 + d] = (_Float16)(a - (float)hi);
    }
}

// ================= launch =================
extern "C" void kernel_launch(void* const* d_in, const int* in_sizes, int n_in,
                              void* d_out, int out_size, void* d_ws, size_t ws_size,
                              hipStream_t stream) {
    const float* inputs   = (const float*)d_in[0];
    const float* noise    = (const float*)d_in[1];
    const float* mu       = (const float*)d_in[2];
    const float* lsig     = (const float*)d_in[3];
    const float* k_w      = (const float*)d_in[4];
    const float* k_b      = (const float*)d_in[5];
    const float* v_w      = (const float*)d_in[6];
    const float* v_b      = (const float*)d_in[7];
    const float* w_ih     = (const float*)d_in[8];
    const float* w_hh     = (const float*)d_in[9];
    const float* b_ih     = (const float*)d_in[10];
    const float* b_hh     = (const float*)d_in[11];
    const float* ln_in_g  = (const float*)d_in[12];
    const float* ln_in_b  = (const float*)d_in[13];
    const float* ln_s_g   = (const float*)d_in[14];
    const float* ln_s_b   = (const float*)d_in[15];
    const float* ln_p_g   = (const float*)d_in[16];
    const float* ln_p_b   = (const float*)d_in[17];
    const float* mlp1_w   = (const float*)d_in[18];
    const float* mlp1_b   = (const float*)d_in[19];
    const float* mlp2_w   = (const float*)d_in[20];
    const float* mlp2_b   = (const float*)d_in[21];
    const float* mlp3_w   = (const float*)d_in[22];
    const float* mlp3_b   = (const float*)d_in[23];
    const float* mlp4_w   = (const float*)d_in[24];
    const float* mlp4_b   = (const float*)d_in[25];
    float* out0 = (float*)d_out;                 // updates [32,8,512]
    float* out1 = (float*)d_out + Bb * NS * Dd;  // s [32,8,256]

    char* wp = (char*)d_ws;
    auto alloc = [&](size_t bytes) -> void* {
        void* p = (void*)wp;
        wp += (bytes + 255) & ~(size_t)255;
        return p;
    };
    const size_t MR = (size_t)Bb * Nn;  // 65536
    _Float16* Apack = (_Float16*)alloc(MR * 512 * 2);           // 67 MB
    _Float16* khalf = (_Float16*)alloc(MR * 512 * 2);           // 67 MB
    _Float16* vT    = (_Float16*)alloc((size_t)Bb * 512 * Nn * 2); // 67 MB
    _Float16* Bkv   = (_Float16*)alloc((size_t)1024 * 512 * 2);
    _Float16* Bih   = (_Float16*)alloc((size_t)1536 * 1024 * 2);
    _Float16* Bhh   = (_Float16*)alloc((size_t)1536 * 1024 * 2);
    _Float16* Bm1   = (_Float16*)alloc((size_t)1024 * 1024 * 2);
    _Float16* Bm2   = (_Float16*)alloc((size_t)1024 * 2048 * 2);
    _Float16* Bm3   = (_Float16*)alloc((size_t)512 * 2048 * 2);
    _Float16* Bm4   = (_Float16*)alloc((size_t)256 * 1024 * 2);
    float* slots    = (float*)alloc((size_t)Bb * NS * Dd * 4);
    float* rawp     = (float*)alloc((size_t)16 * Bb * NS * Dd * 4);  // 8 MB
    float* sumsp    = (float*)alloc((size_t)16 * Bb * NS * 4);
    float* ubuf     = (float*)alloc((size_t)Bb * NS * Dd * 4);
    float* gi       = (float*)alloc((size_t)Bb * NS * 1536 * 4);
    float* gh       = (float*)alloc((size_t)Bb * NS * 1536 * 4);
    _Float16* A2    = (_Float16*)alloc((size_t)512 * 1024 * 2);
    _Float16* P1    = (_Float16*)alloc((size_t)256 * 1024 * 2);
    _Float16* P2    = (_Float16*)alloc((size_t)256 * 2048 * 2);
    _Float16* P3    = (_Float16*)alloc((size_t)256 * 2048 * 2);
    _Float16* P4    = (_Float16*)alloc((size_t)256 * 1024 * 2);

    // ---- prep ----
    megapack_kernel<<<16896, 256, 0, stream>>>(
        k_w, v_w, w_ih, w_hh, mlp1_w, mlp2_w, mlp3_w, mlp4_w,
        Bkv, Bih, Bhh, Bm1, Bm2, Bm3, Bm4);
    pack_ln_single_kernel<<<MR / 4, 256, 0, stream>>>(inputs, ln_in_g, ln_in_b, Apack);
    slots_init_kernel<<<(Bb * NS * Dd) / 256, 256, 0, stream>>>(noise, mu, lsig, slots, A2);

    kv_hgemm_kernel<<<dim3(8, MR / 128), 256, 0, stream>>>(Apack, Bkv, k_b, v_b, khalf, vT);

    for (int it = 0; it < ITERS; ++it) {
        attn_kernel<<<dim3(16, Bb), 256, 0, stream>>>(slots, ln_s_g, ln_s_b, khalf, vT, rawp, sumsp);
        finalize_kernel<<<512, 256, 0, stream>>>(rawp, sumsp, ubuf, out0, A2);
        gru_gemm_kernel<<<dim3(24, 8), 256, 0, stream>>>(A2, Bih, Bhh, b_ih, b_hh, gi, gh);
        gru_elem_kernel<<<512, 256, 0, stream>>>(gi, gh, ubuf, slots, A2);
    }

    // ---- output MLP ----
    lnpack_kernel<<<64, 256, 0, stream>>>(slots, ln_p_g, ln_p_b, P1);
    hgemm64_kernel<1, 1><<<dim3(16, 4), 256, 0, stream>>>(P1, Bm1, mlp1_b, nullptr, P2, 1024, 1024, 1024);
    hgemm64_kernel<1, 1><<<dim3(16, 4), 256, 0, stream>>>(P2, Bm2, mlp2_b, nullptr, P3, 2048, 1024, 1024);
    hgemm64_kernel<1, 1><<<dim3(8, 4), 256, 0, stream>>>(P3, Bm3, mlp3_b, nullptr, P4, 2048, 512, 512);
    hgemm64_kernel<0, 0><<<dim3(4, 4), 256, 0, stream>>>(P4, Bm4, mlp4_b, out1, nullptr, 1024, 256, 256);
}